// Round 3
// baseline (156.112 us; speedup 1.0000x reference)
//
#include <hip/hip_runtime.h>

typedef _Float16 f16;
typedef f16 f16x8 __attribute__((ext_vector_type(8)));
typedef f16 f16x4 __attribute__((ext_vector_type(4)));
typedef f16 f16x2 __attribute__((ext_vector_type(2)));
typedef float f32x4 __attribute__((ext_vector_type(4)));

// ---------------------------------------------------------------------------
// Prep (weights only):
//   W1P[u][w][v]  = f16(W1s[u][v][w])   (128 x 128 x 32)
//   W2P[u][w2][v] = f16(W2[u][v][w2])   (128 x 32 x 32)
// ---------------------------------------------------------------------------
__global__ __launch_bounds__(256) void prep_kernel(
    const float* __restrict__ W1s, const float* __restrict__ W2,
    f16* __restrict__ W1P, f16* __restrict__ W2P)
{
    __shared__ f16 T[32 * 36];
    const int b = blockIdx.x, t = threadIdx.x;

    const float* src; f16* dst; int u, w0, W;
    if (b < 512) { u = b >> 2; w0 = (b & 3) * 32; W = 128; src = W1s; dst = W1P; }
    else         { u = b - 512; w0 = 0;           W = 32;  src = W2;  dst = W2P; }
    {
        int v = t >> 3, wq = t & 7;
        float4 f = *(const float4*)(src + (size_t)(u * 32 + v) * W + w0 + wq * 4);
        T[v * 36 + wq * 4 + 0] = (f16)f.x;
        T[v * 36 + wq * 4 + 1] = (f16)f.y;
        T[v * 36 + wq * 4 + 2] = (f16)f.z;
        T[v * 36 + wq * 4 + 3] = (f16)f.w;
    }
    __syncthreads();
    {
        int w = t >> 3, vr = t & 7;
        f16x4 o = { T[(vr * 4 + 0) * 36 + w], T[(vr * 4 + 1) * 36 + w],
                    T[(vr * 4 + 2) * 36 + w], T[(vr * 4 + 3) * 36 + w] };
        *(f16x4*)(dst + (size_t)u * (W * 32) + (size_t)(w0 + w) * 32 + vr * 4) = o;
    }
}

// ---------------------------------------------------------------------------
// Fully fused network. One block = 32 nodes, 512 threads (8 waves).
// GEMM1: P-form, M=8192 N=128 K=4096. wave = (wm in 0..1) x (cg in 0..3):
//   m-tile 16*wm, cols 32*cg..+31 (two 16-col MFMA tiles).
//   A-frag generated in-register: a[k=v] = s[m][u] * attr[m][v].
//   s-row entirely in VGPRs (no LDS in loop); B double-buffered, 4-iter groups.
// GEMM2: N=32, wave = (wn in 0..1) x (kq in 0..3): cols 16*wn, K-quarter kq,
//   both m-tiles per wave. Partials summed in head via h_lds[4].
// Head: 32x32 MLP per node.
// ---------------------------------------------------------------------------
__global__ __launch_bounds__(512) void fused_kernel(
    const float* __restrict__ node_vec, const float* __restrict__ attr,
    const f16* __restrict__ W1P, const f16* __restrict__ W2P,
    const float* __restrict__ b1s, const float* __restrict__ bias2,
    const float* __restrict__ W3, const float* __restrict__ b3,
    const float* __restrict__ W4, const float* __restrict__ b4,
    float* __restrict__ out)
{
    __shared__ alignas(16) f16 s_lds[32 * 136];
    __shared__ alignas(16) f16 sact_lds[32 * 136];
    __shared__ alignas(16) float W3_lds[32 * 36];
    __shared__ alignas(16) float h_lds[4][32 * 36];

    const int t  = threadIdx.x;
    const int n0 = blockIdx.x * 32;
    const int wv = t >> 6, l = t & 63, lr = l & 15, q = l >> 4;

    // stage s tile: cast node_vec[:, :128] rows to f16 (32 rows x 32 float4)
    #pragma unroll
    for (int i = 0; i < 2; ++i) {
        int idx = t + 512 * i;
        int r = idx >> 5, c4 = idx & 31;
        float4 f = *(const float4*)(node_vec + (size_t)(n0 + r) * 480 + c4 * 4);
        f16x4 o = { (f16)f.x, (f16)f.y, (f16)f.z, (f16)f.w };
        *(f16x4*)(s_lds + r * 136 + c4 * 4) = o;
    }
    if (t < 256) {
        int i = t >> 3, j = (t & 7) * 4;
        *(f32x4*)(W3_lds + i * 36 + j) = *(const f32x4*)(W3 + i * 32 + j);
    }

    // attr fragments for BOTH m-tiles (K-invariant), straight from global f32
    f16x2 attrh[2][4];
    #pragma unroll
    for (int mt = 0; mt < 2; ++mt)
        #pragma unroll
        for (int kk = 0; kk < 4; ++kk) {
            float2 f = *(const float2*)(attr + (size_t)(n0 + 16 * mt + lr) * 32 + q * 8 + kk * 2);
            attrh[mt][kk] = f16x2{ (f16)f.x, (f16)f.y };
        }

    __syncthreads();

    // ================= GEMM1 =================
    const int wm = wv & 1, cg = wv >> 1;

    // whole s-row in registers: 128 f16 = 32 VGPRs
    f16x8 s8[16];
    {
        const f16* srow = s_lds + (16 * wm + lr) * 136;
        #pragma unroll
        for (int ch = 0; ch < 16; ++ch) s8[ch] = *(const f16x8*)(srow + ch * 8);
    }

    const f16* B0 = W1P + (32 * cg + lr) * 32 + q * 8;   // stride 4096 f16 per u
    const f16* B1 = B0 + 16 * 32;

    f16x8 bb[2][2][4];   // [buf][coltile][j]
    #pragma unroll
    for (int j = 0; j < 4; ++j) {
        bb[0][0][j] = *(const f16x8*)(B0 + (size_t)j * 4096);
        bb[0][1][j] = *(const f16x8*)(B1 + (size_t)j * 4096);
    }

    f32x4 acc0 = {0.f, 0.f, 0.f, 0.f}, acc1 = {0.f, 0.f, 0.f, 0.f};
    #pragma unroll
    for (int g = 0; g < 32; ++g) {
        const int buf = g & 1, nbuf = buf ^ 1;
        const int gn = (g + 1 < 32) ? g + 1 : 31;
        #pragma unroll
        for (int j = 0; j < 4; ++j) {
            bb[nbuf][0][j] = *(const f16x8*)(B0 + (size_t)(4 * gn + j) * 4096);
            bb[nbuf][1][j] = *(const f16x8*)(B1 + (size_t)(4 * gn + j) * 4096);
        }
        #pragma unroll
        for (int j = 0; j < 4; ++j) {
            const int c = 4 * g + j;
            f16 sv = s8[c >> 3][c & 7];
            f16x2 sb = { sv, sv };
            f16x8 a;
            #pragma unroll
            for (int kk = 0; kk < 4; ++kk) {
                f16x2 p = sb * attrh[wm][kk];
                a[2 * kk] = p[0]; a[2 * kk + 1] = p[1];
            }
            acc0 = __builtin_amdgcn_mfma_f32_16x16x32_f16(a, bb[buf][0][j], acc0, 0, 0, 0);
            acc1 = __builtin_amdgcn_mfma_f32_16x16x32_f16(a, bb[buf][1][j], acc1, 0, 0, 0);
        }
    }

    // epilogue 1: scale, bias, silu -> sact_lds
    {
        float bv0 = b1s[32 * cg + lr];
        float bv1 = b1s[32 * cg + 16 + lr];
        #pragma unroll
        for (int reg = 0; reg < 4; ++reg) {
            int row = 16 * wm + q * 4 + reg;
            float v0 = acc0[reg] * 0.015625f + bv0;
            float v1 = acc1[reg] * 0.015625f + bv1;
            sact_lds[row * 136 + 32 * cg + lr]      = (f16)(v0 / (1.f + __expf(-v0)));
            sact_lds[row * 136 + 32 * cg + 16 + lr] = (f16)(v1 / (1.f + __expf(-v1)));
        }
    }
    __syncthreads();

    // ================= GEMM2 =================
    const int wn = wv & 1, kq = wv >> 1;   // K-quarter: u in [kq*32, kq*32+32)

    f16x8 sa[2][4];
    #pragma unroll
    for (int mt = 0; mt < 2; ++mt) {
        const f16* srow = sact_lds + (16 * mt + lr) * 136 + kq * 32;
        #pragma unroll
        for (int ch = 0; ch < 4; ++ch) sa[mt][ch] = *(const f16x8*)(srow + ch * 8);
    }

    const f16* B2 = W2P + (size_t)(kq * 32) * 1024 + (16 * wn + lr) * 32 + q * 8;

    f16x8 b2b[2][4];
    #pragma unroll
    for (int j = 0; j < 4; ++j) b2b[0][j] = *(const f16x8*)(B2 + (size_t)j * 1024);

    f32x4 acc20 = {0.f, 0.f, 0.f, 0.f}, acc21 = {0.f, 0.f, 0.f, 0.f};
    #pragma unroll
    for (int g = 0; g < 8; ++g) {
        const int buf = g & 1, nbuf = buf ^ 1;
        const int gn = (g + 1 < 8) ? g + 1 : 7;
        #pragma unroll
        for (int j = 0; j < 4; ++j)
            b2b[nbuf][j] = *(const f16x8*)(B2 + (size_t)(4 * gn + j) * 1024);
        #pragma unroll
        for (int j = 0; j < 4; ++j) {
            const int c = 4 * g + j;
            f16 sv0 = sa[0][c >> 3][c & 7];
            f16 sv1 = sa[1][c >> 3][c & 7];
            f16x2 sb0 = { sv0, sv0 }, sb1 = { sv1, sv1 };
            f16x8 a0, a1;
            #pragma unroll
            for (int kk = 0; kk < 4; ++kk) {
                f16x2 p0 = sb0 * attrh[0][kk];
                f16x2 p1 = sb1 * attrh[1][kk];
                a0[2 * kk] = p0[0]; a0[2 * kk + 1] = p0[1];
                a1[2 * kk] = p1[0]; a1[2 * kk + 1] = p1[1];
            }
            acc20 = __builtin_amdgcn_mfma_f32_16x16x32_f16(a0, b2b[buf][j], acc20, 0, 0, 0);
            acc21 = __builtin_amdgcn_mfma_f32_16x16x32_f16(a1, b2b[buf][j], acc21, 0, 0, 0);
        }
    }
    {
        float bv = (kq == 0) ? bias2[16 * wn + lr] : 0.f;
        #pragma unroll
        for (int reg = 0; reg < 4; ++reg) {
            h_lds[kq][(q * 4 + reg) * 36 + 16 * wn + lr]        = acc20[reg] * 0.015625f + bv;
            h_lds[kq][(16 + q * 4 + reg) * 36 + 16 * wn + lr]   = acc21[reg] * 0.015625f + bv;
        }
    }
    __syncthreads();

    // ================= head =================
    {
        int hn = t >> 4, j0 = (t & 15) * 2;
        float a0 = 0.f, a1 = 0.f;
        #pragma unroll
        for (int i = 0; i < 32; ++i) {
            float hv = h_lds[0][hn * 36 + i] + h_lds[1][hn * 36 + i]
                     + h_lds[2][hn * 36 + i] + h_lds[3][hn * 36 + i];
            a0 += hv * W3_lds[i * 36 + j0];
            a1 += hv * W3_lds[i * 36 + j0 + 1];
        }
        const float inv = 0.17677669529663687f;  // 1/sqrt(32)
        float t0 = a0 * inv + b3[j0];
        float t1 = a1 * inv + b3[j0 + 1];
        float g0 = t0 / (1.f + __expf(-t0));
        float g1 = t1 / (1.f + __expf(-t1));
        float p = g0 * W4[j0] * inv + g1 * W4[j0 + 1] * inv;
        p += __shfl_xor(p, 1);
        p += __shfl_xor(p, 2);
        p += __shfl_xor(p, 4);
        p += __shfl_xor(p, 8);
        if ((t & 15) == 0) out[n0 + hn] = p + b4[0];
    }
}

// ---------------------------------------------------------------------------
extern "C" void kernel_launch(void* const* d_in, const int* in_sizes, int n_in,
                              void* d_out, int out_size, void* d_ws, size_t ws_size,
                              hipStream_t stream)
{
    const float* node_vec = (const float*)d_in[0];
    const float* attr     = (const float*)d_in[1];
    const float* W1s      = (const float*)d_in[2];
    const float* b1s      = (const float*)d_in[3];
    // d_in[4..7] (W1g,b1g,W1v1,W1v2) are dead code w.r.t. pred_energy
    const float* W2       = (const float*)d_in[8];
    const float* b2       = (const float*)d_in[9];
    const float* W3       = (const float*)d_in[10];
    const float* b3       = (const float*)d_in[11];
    const float* W4       = (const float*)d_in[12];
    const float* b4       = (const float*)d_in[13];
    float* out = (float*)d_out;

    char* ws = (char*)d_ws;
    f16* W1P = (f16*)(ws);                  // 128*128*32*2 = 1 MiB
    f16* W2P = (f16*)(ws + (1u << 20));     // 128*32*32*2  = 256 KiB

    prep_kernel<<<640, 256, 0, stream>>>(W1s, W2, W1P, W2P);
    fused_kernel<<<256, 512, 0, stream>>>(node_vec, attr, W1P, W2P,
                                          b1s, b2, W3, b3, W4, b4, out);
}

// Round 4
// 121.380 us; speedup vs baseline: 1.2861x; 1.2861x over previous
//
#include <hip/hip_runtime.h>

typedef _Float16 f16;
typedef f16 f16x8 __attribute__((ext_vector_type(8)));
typedef f16 f16x4 __attribute__((ext_vector_type(4)));
typedef f16 f16x2 __attribute__((ext_vector_type(2)));
typedef float f32x4 __attribute__((ext_vector_type(4)));

union F8 { uint4 u4; f16x8 v; f16x2 h[4]; f16 e[8]; };

// ---------------------------------------------------------------------------
// Prep:
//   s_f16[n][u]    = f16(node_vec[n][u])   (8192 x 128)
//   attr_f16[n][v] = f16(attr[n][v])       (8192 x 32)
//   W1P[u][w][v]   = f16(W1s[u][v][w])     (128 x 128 x 32)
//   W2P[u][w2][v]  = f16(W2[u][v][w2])     (128 x 32 x 32)
// ---------------------------------------------------------------------------
__global__ __launch_bounds__(256) void prep_kernel(
    const float* __restrict__ node_vec, const float* __restrict__ attr,
    const float* __restrict__ W1s, const float* __restrict__ W2,
    f16* __restrict__ s_f16, f16* __restrict__ attr_f16,
    f16* __restrict__ W1P, f16* __restrict__ W2P)
{
    __shared__ f16 T[32 * 36];
    const int b = blockIdx.x, t = threadIdx.x;

    if (b < 640) {
        const float* src; f16* dst; int u, w0, W;
        if (b < 512) { u = b >> 2; w0 = (b & 3) * 32; W = 128; src = W1s; dst = W1P; }
        else         { u = b - 512; w0 = 0;           W = 32;  src = W2;  dst = W2P; }
        {
            int v = t >> 3, wq = t & 7;
            float4 f = *(const float4*)(src + (size_t)(u * 32 + v) * W + w0 + wq * 4);
            T[v * 36 + wq * 4 + 0] = (f16)f.x;
            T[v * 36 + wq * 4 + 1] = (f16)f.y;
            T[v * 36 + wq * 4 + 2] = (f16)f.z;
            T[v * 36 + wq * 4 + 3] = (f16)f.w;
        }
        __syncthreads();
        {
            int w = t >> 3, vr = t & 7;
            f16x4 o = { T[(vr * 4 + 0) * 36 + w], T[(vr * 4 + 1) * 36 + w],
                        T[(vr * 4 + 2) * 36 + w], T[(vr * 4 + 3) * 36 + w] };
            *(f16x4*)(dst + (size_t)u * (W * 32) + (size_t)(w0 + w) * 32 + vr * 4) = o;
        }
    } else if (b < 1152) {
        int j = (b - 640) * 256 + t;
        int n = j >> 4, c = j & 15;
        float4 a  = *(const float4*)(node_vec + (size_t)n * 480 + c * 8);
        float4 bb = *(const float4*)(node_vec + (size_t)n * 480 + c * 8 + 4);
        f16x8 ev = { (f16)a.x, (f16)a.y, (f16)a.z, (f16)a.w,
                     (f16)bb.x, (f16)bb.y, (f16)bb.z, (f16)bb.w };
        *(f16x8*)(s_f16 + (size_t)n * 128 + c * 8) = ev;
    } else {
        int j = (b - 1152) * 256 + t;
        int n = j >> 2, c = j & 3;
        float4 a  = *(const float4*)(attr + (size_t)n * 32 + c * 8);
        float4 bb = *(const float4*)(attr + (size_t)n * 32 + c * 8 + 4);
        f16x8 ev = { (f16)a.x, (f16)a.y, (f16)a.z, (f16)a.w,
                     (f16)bb.x, (f16)bb.y, (f16)bb.z, (f16)bb.w };
        *(f16x8*)(attr_f16 + (size_t)n * 32 + c * 8) = ev;
    }
}

// ---------------------------------------------------------------------------
// K1: GEMM1 + silu.  Block = 64 rows x 64 cols.  Grid (128 mg, 2 ncs).
// 4 waves x disjoint 16-col strips; each wave: 4 m-tiles x K=4096 (128 u).
// B streamed from L2 with depth-8 register ring; s via LDS octet reads.
// No barriers after staging, no cross-wave reduction.
// ---------------------------------------------------------------------------
__global__ __launch_bounds__(256, 2) void gemm1_kernel(
    const f16* __restrict__ s_f16, const f16* __restrict__ attr_f16,
    const f16* __restrict__ W1P, const float* __restrict__ b1s,
    f16* __restrict__ s_act)
{
    __shared__ alignas(16) f16 s_lds[64 * 136];

    const int t  = threadIdx.x;
    const int n0 = blockIdx.x * 64;
    const int l  = t & 63, lr = l & 15, q = l >> 4;
    const int c0 = blockIdx.y * 64 + (t >> 6) * 16;   // wave's 16-col strip

    // prime B ring (depth 8): frag(u) = W1P[u][c0+lr][q*8..+7], stride 4096 f16/u
    const f16* Bp = W1P + ((size_t)(c0 + lr)) * 32 + q * 8;
    f16x8 B[8];
    #pragma unroll
    for (int j = 0; j < 8; ++j)
        B[j] = *(const f16x8*)(Bp + (size_t)j * 4096);

    // attr fragments (K-invariant): af[mt] = attr_f16[n0+16mt+lr][q*8..+7]
    F8 af[4];
    #pragma unroll
    for (int mt = 0; mt < 4; ++mt)
        af[mt].v = *(const f16x8*)(attr_f16 + (size_t)(n0 + 16 * mt + lr) * 32 + q * 8);

    // stage s tile (64 x 128 f16, padded rows 136)
    #pragma unroll
    for (int i = 0; i < 4; ++i) {
        int ch = t + 256 * i;
        int r = ch >> 4, c8 = ch & 15;
        *(uint4*)(s_lds + r * 136 + c8 * 8) =
            *(const uint4*)(s_f16 + (size_t)(n0 + r) * 128 + c8 * 8);
    }
    __syncthreads();

    f32x4 acc[4] = { {0,0,0,0}, {0,0,0,0}, {0,0,0,0}, {0,0,0,0} };

    // s octets, double-buffered (same address across q -> LDS broadcast)
    F8 s8[2][4];
    #pragma unroll
    for (int mt = 0; mt < 4; ++mt)
        s8[0][mt].v = *(const f16x8*)(s_lds + (16 * mt + lr) * 136);

    #pragma unroll 4
    for (int uo = 0; uo < 16; ++uo) {
        const int cur = uo & 1, nxt = cur ^ 1;
        const int uon = (uo + 1 < 16) ? uo + 1 : 15;
        #pragma unroll
        for (int mt = 0; mt < 4; ++mt)
            s8[nxt][mt].v = *(const f16x8*)(s_lds + (16 * mt + lr) * 136 + uon * 8);
        #pragma unroll
        for (int j = 0; j < 8; ++j) {
            const int u = uo * 8 + j;
            f16x8 bf = B[j];
            const int un = (u + 8 < 128) ? (u + 8) : u;    // tail reload, harmless
            B[j] = *(const f16x8*)(Bp + (size_t)un * 4096);
            #pragma unroll
            for (int mt = 0; mt < 4; ++mt) {
                f16 sv = s8[cur][mt].e[j];
                f16x2 sb = { sv, sv };
                F8 a;
                #pragma unroll
                for (int kk = 0; kk < 4; ++kk)
                    a.h[kk] = sb * af[mt].h[kk];
                acc[mt] = __builtin_amdgcn_mfma_f32_16x16x32_f16(a.v, bf, acc[mt], 0, 0, 0);
            }
        }
    }

    // epilogue: scale, bias, silu -> s_act (each wave owns its outputs)
    const float bv = b1s[c0 + lr];
    #pragma unroll
    for (int mt = 0; mt < 4; ++mt)
        #pragma unroll
        for (int reg = 0; reg < 4; ++reg) {
            int row = n0 + 16 * mt + q * 4 + reg;     // C layout: col=lr, row=q*4+reg
            float v = acc[mt][reg] * 0.015625f + bv;
            s_act[(size_t)row * 128 + c0 + lr] = (f16)(v / (1.f + __expf(-v)));
        }
}

// ---------------------------------------------------------------------------
// K2: GEMM2 + head.  Block = 32 rows x all 32 cols.  Grid 256.
// 4 waves split u2 (32 each), depth-8 B ring; one LDS reduction; fused head.
// ---------------------------------------------------------------------------
__global__ __launch_bounds__(256, 2) void gemm2_head_kernel(
    const f16* __restrict__ s_act, const f16* __restrict__ attr_f16,
    const f16* __restrict__ W2P, const float* __restrict__ b2,
    const float* __restrict__ W3, const float* __restrict__ b3,
    const float* __restrict__ W4, const float* __restrict__ b4,
    float* __restrict__ out)
{
    __shared__ alignas(16) f16 s_lds[32 * 136];
    __shared__ alignas(16) float red[4][32 * 36];
    __shared__ alignas(16) float W3_lds[32 * 36];
    __shared__ alignas(16) float h_lds[32 * 36];

    const int t  = threadIdx.x;
    const int n0 = blockIdx.x * 32;
    const int wv = t >> 6, l = t & 63, lr = l & 15, q = l >> 4;
    const int u0 = wv * 32;

    // prime B ring: frag(u2, nt) = W2P[u2][16nt+lr][q*8..+7], stride 1024 f16/u2
    const f16* B2p = W2P + ((size_t)u0 * 32 + lr) * 32 + q * 8;
    f16x8 B0[8], B1[8];
    #pragma unroll
    for (int j = 0; j < 8; ++j) {
        B0[j] = *(const f16x8*)(B2p + (size_t)j * 1024);
        B1[j] = *(const f16x8*)(B2p + (size_t)j * 1024 + 512);
    }

    F8 af[2];
    #pragma unroll
    for (int mt = 0; mt < 2; ++mt)
        af[mt].v = *(const f16x8*)(attr_f16 + (size_t)(n0 + 16 * mt + lr) * 32 + q * 8);

    // stage s_act tile (32 x 128) and W3 (32 x 32, stride 36)
    #pragma unroll
    for (int i = 0; i < 2; ++i) {
        int ch = t + 256 * i;
        int r = ch >> 4, c8 = ch & 15;
        *(uint4*)(s_lds + r * 136 + c8 * 8) =
            *(const uint4*)(s_act + (size_t)(n0 + r) * 128 + c8 * 8);
    }
    { int i = t >> 3, jj = (t & 7) * 4;
      *(f32x4*)(W3_lds + i * 36 + jj) = *(const f32x4*)(W3 + i * 32 + jj); }
    __syncthreads();

    f32x4 acc[2][2] = { { {0,0,0,0}, {0,0,0,0} }, { {0,0,0,0}, {0,0,0,0} } };

    F8 s8[2][2];
    #pragma unroll
    for (int mt = 0; mt < 2; ++mt)
        s8[0][mt].v = *(const f16x8*)(s_lds + (16 * mt + lr) * 136 + u0);

    #pragma unroll
    for (int uo = 0; uo < 4; ++uo) {
        const int cur = uo & 1, nxt = cur ^ 1;
        const int uon = (uo + 1 < 4) ? uo + 1 : 3;
        #pragma unroll
        for (int mt = 0; mt < 2; ++mt)
            s8[nxt][mt].v = *(const f16x8*)(s_lds + (16 * mt + lr) * 136 + u0 + uon * 8);
        #pragma unroll
        for (int j = 0; j < 8; ++j) {
            const int k = uo * 8 + j;                  // 0..31 within subrange
            f16x8 bf0 = B0[j], bf1 = B1[j];
            const int kn = (k + 8 < 32) ? (k + 8) : k;
            B0[j] = *(const f16x8*)(B2p + (size_t)kn * 1024);
            B1[j] = *(const f16x8*)(B2p + (size_t)kn * 1024 + 512);
            #pragma unroll
            for (int mt = 0; mt < 2; ++mt) {
                f16 sv = s8[cur][mt].e[j];
                f16x2 sb = { sv, sv };
                F8 a;
                #pragma unroll
                for (int kk = 0; kk < 4; ++kk)
                    a.h[kk] = sb * af[mt].h[kk];
                acc[mt][0] = __builtin_amdgcn_mfma_f32_16x16x32_f16(a.v, bf0, acc[mt][0], 0, 0, 0);
                acc[mt][1] = __builtin_amdgcn_mfma_f32_16x16x32_f16(a.v, bf1, acc[mt][1], 0, 0, 0);
            }
        }
    }

    // cross-wave u2 reduction
    #pragma unroll
    for (int mt = 0; mt < 2; ++mt)
        #pragma unroll
        for (int nt = 0; nt < 2; ++nt)
            #pragma unroll
            for (int reg = 0; reg < 4; ++reg)
                red[wv][(16 * mt + q * 4 + reg) * 36 + 16 * nt + lr] = acc[mt][nt][reg];
    __syncthreads();

    // h = sum/64 + b2 -> h_lds
    {
        int row = t >> 3, c4 = (t & 7) * 4;
        f32x4 s = *(const f32x4*)(&red[0][row * 36 + c4]);
        s = s + *(const f32x4*)(&red[1][row * 36 + c4]);
        s = s + *(const f32x4*)(&red[2][row * 36 + c4]);
        s = s + *(const f32x4*)(&red[3][row * 36 + c4]);
        #pragma unroll
        for (int e = 0; e < 4; ++e)
            h_lds[row * 36 + c4 + e] = s[e] * 0.015625f + b2[c4 + e];
    }
    __syncthreads();

    // head: 8 threads per node, 4 output-j each
    {
        int node = t >> 3, j4 = (t & 7) * 4;
        float a0 = 0.f, a1 = 0.f, a2 = 0.f, a3 = 0.f;
        #pragma unroll
        for (int i = 0; i < 32; ++i) {
            float hv = h_lds[node * 36 + i];
            a0 += hv * W3_lds[i * 36 + j4 + 0];
            a1 += hv * W3_lds[i * 36 + j4 + 1];
            a2 += hv * W3_lds[i * 36 + j4 + 2];
            a3 += hv * W3_lds[i * 36 + j4 + 3];
        }
        const float inv = 0.17677669529663687f;  // 1/sqrt(32)
        float p = 0.f;
        float aa[4] = { a0, a1, a2, a3 };
        #pragma unroll
        for (int e = 0; e < 4; ++e) {
            float tv = aa[e] * inv + b3[j4 + e];
            float g  = tv / (1.f + __expf(-tv));
            p += g * W4[j4 + e] * inv;
        }
        p += __shfl_xor(p, 1);
        p += __shfl_xor(p, 2);
        p += __shfl_xor(p, 4);
        if ((t & 7) == 0) out[n0 + node] = p + b4[0];
    }
}

// ---------------------------------------------------------------------------
extern "C" void kernel_launch(void* const* d_in, const int* in_sizes, int n_in,
                              void* d_out, int out_size, void* d_ws, size_t ws_size,
                              hipStream_t stream)
{
    const float* node_vec = (const float*)d_in[0];
    const float* attr     = (const float*)d_in[1];
    const float* W1s      = (const float*)d_in[2];
    const float* b1s      = (const float*)d_in[3];
    // d_in[4..7] (W1g,b1g,W1v1,W1v2) are dead code w.r.t. pred_energy
    const float* W2       = (const float*)d_in[8];
    const float* b2       = (const float*)d_in[9];
    const float* W3       = (const float*)d_in[10];
    const float* b3       = (const float*)d_in[11];
    const float* W4       = (const float*)d_in[12];
    const float* b4       = (const float*)d_in[13];
    float* out = (float*)d_out;

    char* ws = (char*)d_ws;
    f16* s_f16    = (f16*)(ws);                    // 8192*128*2 = 2 MiB
    f16* attr_f16 = (f16*)(ws + (2u   << 20));     // 512 KiB
    f16* W1P      = (f16*)(ws + (2560u << 10));    // 1 MiB
    f16* W2P      = (f16*)(ws + (3584u << 10));    // 256 KiB
    f16* s_act    = (f16*)(ws + (3840u << 10));    // 2 MiB

    prep_kernel<<<1280, 256, 0, stream>>>(node_vec, attr, W1s, W2,
                                          s_f16, attr_f16, W1P, W2P);
    gemm1_kernel<<<dim3(128, 2), 256, 0, stream>>>(s_f16, attr_f16, W1P, b1s, s_act);
    gemm2_head_kernel<<<256, 256, 0, stream>>>(s_act, attr_f16, W2P, b2,
                                               W3, b3, W4, b4, out);
}

// Round 5
// 117.029 us; speedup vs baseline: 1.3340x; 1.0372x over previous
//
#include <hip/hip_runtime.h>

typedef _Float16 f16;
typedef f16 f16x8 __attribute__((ext_vector_type(8)));
typedef f16 f16x4 __attribute__((ext_vector_type(4)));
typedef f16 f16x2 __attribute__((ext_vector_type(2)));
typedef float f32x4 __attribute__((ext_vector_type(4)));

union F8 { uint4 u4; f16x8 v; f16x2 h[4]; f16 e[8]; };

// ---------------------------------------------------------------------------
// Prep (weights only):
//   W1P[u][w][v]  = f16(W1s[u][v][w])   (128 x 128 x 32)
//   W2P[u][w2][v] = f16(W2[u][v][w2])   (128 x 32 x 32)
// ---------------------------------------------------------------------------
__global__ __launch_bounds__(256) void prep_kernel(
    const float* __restrict__ W1s, const float* __restrict__ W2,
    f16* __restrict__ W1P, f16* __restrict__ W2P)
{
    __shared__ f16 T[32 * 36];
    const int b = blockIdx.x, t = threadIdx.x;

    const float* src; f16* dst; int u, w0, W;
    if (b < 512) { u = b >> 2; w0 = (b & 3) * 32; W = 128; src = W1s; dst = W1P; }
    else         { u = b - 512; w0 = 0;           W = 32;  src = W2;  dst = W2P; }
    {
        int v = t >> 3, wq = t & 7;
        float4 f = *(const float4*)(src + (size_t)(u * 32 + v) * W + w0 + wq * 4);
        T[v * 36 + wq * 4 + 0] = (f16)f.x;
        T[v * 36 + wq * 4 + 1] = (f16)f.y;
        T[v * 36 + wq * 4 + 2] = (f16)f.z;
        T[v * 36 + wq * 4 + 3] = (f16)f.w;
    }
    __syncthreads();
    {
        int w = t >> 3, vr = t & 7;
        f16x4 o = { T[(vr * 4 + 0) * 36 + w], T[(vr * 4 + 1) * 36 + w],
                    T[(vr * 4 + 2) * 36 + w], T[(vr * 4 + 3) * 36 + w] };
        *(f16x4*)(dst + (size_t)u * (W * 32) + (size_t)(w0 + w) * 32 + vr * 4) = o;
    }
}

// ---------------------------------------------------------------------------
// K1: GEMM1 + silu.  Block = 32 rows x 64 cols, 256 thr (4 waves = 4 col
// strips).  Grid (256, 2) = 512 blocks -> 2 blocks/CU, 2 waves/SIMD.
// ALL register arrays indexed by compile-time constants (full unroll) so
// nothing can be demoted to scratch.  B streamed from L2, depth-8 ring.
// s/attr cast from f32 inline (no separate cast kernel).
// ---------------------------------------------------------------------------
__global__ __launch_bounds__(256, 2) void gemm1_kernel(
    const float* __restrict__ node_vec, const float* __restrict__ attr,
    const f16* __restrict__ W1P, const float* __restrict__ b1s,
    f16* __restrict__ s_act)
{
    __shared__ alignas(16) f16 s_lds[32 * 136];

    const int t  = threadIdx.x;
    const int n0 = blockIdx.x * 32;
    const int l  = t & 63, lr = l & 15, q = l >> 4;
    const int c0 = blockIdx.y * 64 + (t >> 6) * 16;   // wave's 16-col strip

    // stage s tile: 32 rows x 128 cols, f32 -> f16
    #pragma unroll
    for (int i = 0; i < 4; ++i) {
        int idx = t + 256 * i;
        int r = idx >> 5, c4 = idx & 31;
        float4 f = *(const float4*)(node_vec + (size_t)(n0 + r) * 480 + c4 * 4);
        f16x4 o = { (f16)f.x, (f16)f.y, (f16)f.z, (f16)f.w };
        *(f16x4*)(s_lds + r * 136 + c4 * 4) = o;
    }

    // attr fragments (K-invariant), cast from f32
    F8 af0, af1;
    #pragma unroll
    for (int kk = 0; kk < 4; ++kk) {
        float2 fa = *(const float2*)(attr + (size_t)(n0 + lr) * 32 + q * 8 + kk * 2);
        float2 fb = *(const float2*)(attr + (size_t)(n0 + 16 + lr) * 32 + q * 8 + kk * 2);
        af0.h[kk] = f16x2{ (f16)fa.x, (f16)fa.y };
        af1.h[kk] = f16x2{ (f16)fb.x, (f16)fb.y };
    }

    // prime B ring (depth 8): frag(u) = W1P[u][c0+lr][q*8..+7], 4096 f16/u
    const f16* Bp = W1P + ((size_t)(c0 + lr)) * 32 + q * 8;
    f16x8 B[8];
    #pragma unroll
    for (int j = 0; j < 8; ++j)
        B[j] = *(const f16x8*)(Bp + (size_t)j * 4096);

    __syncthreads();

    f32x4 acc0 = {0.f, 0.f, 0.f, 0.f}, acc1 = {0.f, 0.f, 0.f, 0.f};

    F8 s8[2][2];   // [buf][mt] — only constant indices below (full unroll)
    s8[0][0].v = *(const f16x8*)(s_lds + lr * 136);
    s8[0][1].v = *(const f16x8*)(s_lds + (16 + lr) * 136);

    #pragma unroll
    for (int uo = 0; uo < 16; ++uo) {
        const int cur = uo & 1, nxt = cur ^ 1;      // constants: loop fully unrolled
        const int uon = (uo + 1 < 16) ? uo + 1 : 15;
        s8[nxt][0].v = *(const f16x8*)(s_lds + lr * 136 + uon * 8);
        s8[nxt][1].v = *(const f16x8*)(s_lds + (16 + lr) * 136 + uon * 8);
        #pragma unroll
        for (int j = 0; j < 8; ++j) {
            const int u = uo * 8 + j;
            f16x8 bf = B[j];
            const int un = (u + 8 < 128) ? (u + 8) : u;   // constant
            B[j] = *(const f16x8*)(Bp + (size_t)un * 4096);
            f16 sv0 = s8[cur][0].e[j];
            f16 sv1 = s8[cur][1].e[j];
            f16x2 sb0 = { sv0, sv0 }, sb1 = { sv1, sv1 };
            F8 a0, a1;
            #pragma unroll
            for (int kk = 0; kk < 4; ++kk) {
                a0.h[kk] = sb0 * af0.h[kk];
                a1.h[kk] = sb1 * af1.h[kk];
            }
            acc0 = __builtin_amdgcn_mfma_f32_16x16x32_f16(a0.v, bf, acc0, 0, 0, 0);
            acc1 = __builtin_amdgcn_mfma_f32_16x16x32_f16(a1.v, bf, acc1, 0, 0, 0);
        }
    }

    // epilogue: scale, bias, silu -> s_act.  C layout: col=lr, row=q*4+reg
    const float bv = b1s[c0 + lr];
    #pragma unroll
    for (int reg = 0; reg < 4; ++reg) {
        float v0 = acc0[reg] * 0.015625f + bv;
        float v1 = acc1[reg] * 0.015625f + bv;
        s_act[(size_t)(n0 + q * 4 + reg) * 128 + c0 + lr] =
            (f16)(v0 / (1.f + __expf(-v0)));
        s_act[(size_t)(n0 + 16 + q * 4 + reg) * 128 + c0 + lr] =
            (f16)(v1 / (1.f + __expf(-v1)));
    }
}

// ---------------------------------------------------------------------------
// K2: GEMM2 + head.  Block = 32 rows x all 32 cols, 256 thr.  Grid 256.
// 4 waves split u2 (32 each); depth-8 B ring x 2 col-tiles; LDS reduction;
// fused 32x32 head.  All register arrays constant-indexed.
// ---------------------------------------------------------------------------
__global__ __launch_bounds__(256, 2) void gemm2_head_kernel(
    const f16* __restrict__ s_act, const float* __restrict__ attr,
    const f16* __restrict__ W2P, const float* __restrict__ b2,
    const float* __restrict__ W3, const float* __restrict__ b3,
    const float* __restrict__ W4, const float* __restrict__ b4,
    float* __restrict__ out)
{
    __shared__ alignas(16) f16 s_lds[32 * 136];
    __shared__ alignas(16) float red[4][32 * 36];
    __shared__ alignas(16) float W3_lds[32 * 36];
    __shared__ alignas(16) float h_lds[32 * 36];

    const int t  = threadIdx.x;
    const int n0 = blockIdx.x * 32;
    const int wv = t >> 6, l = t & 63, lr = l & 15, q = l >> 4;
    const int u0 = wv * 32;

    // prime B rings: frag(u2,nt) = W2P[u2][16nt+lr][q*8..+7], 1024 f16/u2
    const f16* B2p = W2P + ((size_t)u0 * 32 + lr) * 32 + q * 8;
    f16x8 B0[8], B1[8];
    #pragma unroll
    for (int j = 0; j < 8; ++j) {
        B0[j] = *(const f16x8*)(B2p + (size_t)j * 1024);
        B1[j] = *(const f16x8*)(B2p + (size_t)j * 1024 + 512);
    }

    F8 af0, af1;
    #pragma unroll
    for (int kk = 0; kk < 4; ++kk) {
        float2 fa = *(const float2*)(attr + (size_t)(n0 + lr) * 32 + q * 8 + kk * 2);
        float2 fb = *(const float2*)(attr + (size_t)(n0 + 16 + lr) * 32 + q * 8 + kk * 2);
        af0.h[kk] = f16x2{ (f16)fa.x, (f16)fa.y };
        af1.h[kk] = f16x2{ (f16)fb.x, (f16)fb.y };
    }

    // stage s_act tile (32 x 128) and W3 (32 x 32, stride 36)
    #pragma unroll
    for (int i = 0; i < 2; ++i) {
        int ch = t + 256 * i;
        int r = ch >> 4, c8 = ch & 15;
        *(uint4*)(s_lds + r * 136 + c8 * 8) =
            *(const uint4*)(s_act + (size_t)(n0 + r) * 128 + c8 * 8);
    }
    { int i = t >> 3, jj = (t & 7) * 4;
      *(f32x4*)(W3_lds + i * 36 + jj) = *(const f32x4*)(W3 + i * 32 + jj); }
    __syncthreads();

    f32x4 acc00 = {0,0,0,0}, acc01 = {0,0,0,0};
    f32x4 acc10 = {0,0,0,0}, acc11 = {0,0,0,0};

    F8 s8[2][2];
    s8[0][0].v = *(const f16x8*)(s_lds + lr * 136 + u0);
    s8[0][1].v = *(const f16x8*)(s_lds + (16 + lr) * 136 + u0);

    #pragma unroll
    for (int uo = 0; uo < 4; ++uo) {
        const int cur = uo & 1, nxt = cur ^ 1;
        const int uon = (uo + 1 < 4) ? uo + 1 : 3;
        s8[nxt][0].v = *(const f16x8*)(s_lds + lr * 136 + u0 + uon * 8);
        s8[nxt][1].v = *(const f16x8*)(s_lds + (16 + lr) * 136 + u0 + uon * 8);
        #pragma unroll
        for (int j = 0; j < 8; ++j) {
            const int k = uo * 8 + j;
            f16x8 bf0 = B0[j], bf1 = B1[j];
            const int kn = (k + 8 < 32) ? (k + 8) : k;
            B0[j] = *(const f16x8*)(B2p + (size_t)kn * 1024);
            B1[j] = *(const f16x8*)(B2p + (size_t)kn * 1024 + 512);
            f16 sv0 = s8[cur][0].e[j];
            f16 sv1 = s8[cur][1].e[j];
            f16x2 sb0 = { sv0, sv0 }, sb1 = { sv1, sv1 };
            F8 a0, a1;
            #pragma unroll
            for (int kk = 0; kk < 4; ++kk) {
                a0.h[kk] = sb0 * af0.h[kk];
                a1.h[kk] = sb1 * af1.h[kk];
            }
            acc00 = __builtin_amdgcn_mfma_f32_16x16x32_f16(a0.v, bf0, acc00, 0, 0, 0);
            acc01 = __builtin_amdgcn_mfma_f32_16x16x32_f16(a0.v, bf1, acc01, 0, 0, 0);
            acc10 = __builtin_amdgcn_mfma_f32_16x16x32_f16(a1.v, bf0, acc10, 0, 0, 0);
            acc11 = __builtin_amdgcn_mfma_f32_16x16x32_f16(a1.v, bf1, acc11, 0, 0, 0);
        }
    }

    // cross-wave u2 reduction
    #pragma unroll
    for (int reg = 0; reg < 4; ++reg) {
        red[wv][(q * 4 + reg) * 36 + lr]           = acc00[reg];
        red[wv][(q * 4 + reg) * 36 + 16 + lr]      = acc01[reg];
        red[wv][(16 + q * 4 + reg) * 36 + lr]      = acc10[reg];
        red[wv][(16 + q * 4 + reg) * 36 + 16 + lr] = acc11[reg];
    }
    __syncthreads();

    // h = sum/64 + b2 -> h_lds
    {
        int row = t >> 3, c4 = (t & 7) * 4;
        f32x4 s = *(const f32x4*)(&red[0][row * 36 + c4]);
        s = s + *(const f32x4*)(&red[1][row * 36 + c4]);
        s = s + *(const f32x4*)(&red[2][row * 36 + c4]);
        s = s + *(const f32x4*)(&red[3][row * 36 + c4]);
        #pragma unroll
        for (int e = 0; e < 4; ++e)
            h_lds[row * 36 + c4 + e] = s[e] * 0.015625f + b2[c4 + e];
    }
    __syncthreads();

    // head: 8 threads per node, 4 output-j each
    {
        int node = t >> 3, j4 = (t & 7) * 4;
        float a0 = 0.f, a1 = 0.f, a2 = 0.f, a3 = 0.f;
        #pragma unroll
        for (int i = 0; i < 32; ++i) {
            float hv = h_lds[node * 36 + i];
            a0 += hv * W3_lds[i * 36 + j4 + 0];
            a1 += hv * W3_lds[i * 36 + j4 + 1];
            a2 += hv * W3_lds[i * 36 + j4 + 2];
            a3 += hv * W3_lds[i * 36 + j4 + 3];
        }
        const float inv = 0.17677669529663687f;  // 1/sqrt(32)
        float p = 0.f;
        float aa[4] = { a0, a1, a2, a3 };
        #pragma unroll
        for (int e = 0; e < 4; ++e) {
            float tv = aa[e] * inv + b3[j4 + e];
            float g  = tv / (1.f + __expf(-tv));
            p += g * W4[j4 + e] * inv;
        }
        p += __shfl_xor(p, 1);
        p += __shfl_xor(p, 2);
        p += __shfl_xor(p, 4);
        if ((t & 7) == 0) out[n0 + node] = p + b4[0];
    }
}

// ---------------------------------------------------------------------------
extern "C" void kernel_launch(void* const* d_in, const int* in_sizes, int n_in,
                              void* d_out, int out_size, void* d_ws, size_t ws_size,
                              hipStream_t stream)
{
    const float* node_vec = (const float*)d_in[0];
    const float* attr     = (const float*)d_in[1];
    const float* W1s      = (const float*)d_in[2];
    const float* b1s      = (const float*)d_in[3];
    // d_in[4..7] (W1g,b1g,W1v1,W1v2) are dead code w.r.t. pred_energy
    const float* W2       = (const float*)d_in[8];
    const float* b2       = (const float*)d_in[9];
    const float* W3       = (const float*)d_in[10];
    const float* b3       = (const float*)d_in[11];
    const float* W4       = (const float*)d_in[12];
    const float* b4       = (const float*)d_in[13];
    float* out = (float*)d_out;

    char* ws = (char*)d_ws;
    f16* W1P   = (f16*)(ws);                  // 128*128*32*2 = 1 MiB
    f16* W2P   = (f16*)(ws + (1u << 20));     // 128*32*32*2  = 256 KiB
    f16* s_act = (f16*)(ws + (1280u << 10));  // 8192*128*2   = 2 MiB

    prep_kernel<<<640, 256, 0, stream>>>(W1s, W2, W1P, W2P);
    gemm1_kernel<<<dim3(256, 2), 256, 0, stream>>>(node_vec, attr, W1P, b1s, s_act);
    gemm2_head_kernel<<<256, 256, 0, stream>>>(s_act, attr, W2P, b2,
                                               W3, b3, W4, b4, out);
}